// Round 8
// baseline (62.902 us; speedup 1.0000x reference)
//
#include <hip/hip_runtime.h>

#define CDIM 256
#define NDET 900
#define NMAP 100
#define NPTS 20
#define GPB 4
#define NDBLK (NDET / GPB)    // 225
#define NMBLK (NMAP / GPB)    // 25
#define NBLK (NDBLK + NMBLK)  // 250

__device__ __forceinline__ const float* lvlPtr(int l, const float* p2, const float* p3,
                                               const float* p4, const float* p5) {
    return (l == 0) ? p2 : (l == 1) ? p3 : (l == 2) ? p4 : p5;
}
__device__ __forceinline__ int lvlHW(int l) {
    return (l == 0) ? 19200 : (l == 1) ? 4800 : (l == 2) ? 1200 : 300;
}

__global__ __launch_bounds__(256) void autonav_fused(
    const float* __restrict__ p2, const float* __restrict__ p3,
    const float* __restrict__ p4, const float* __restrict__ p5,
    const float* __restrict__ Kin, const float* __restrict__ Ein,
    const float* __restrict__ det3d, const float* __restrict__ detfull,
    const float* __restrict__ mapanch,
    const float* __restrict__ W1d, const float* __restrict__ b1d,
    const float* __restrict__ Wcd, const float* __restrict__ bcd,
    const float* __restrict__ Wod, const float* __restrict__ bod,
    const float* __restrict__ W1m, const float* __restrict__ b1m,
    const float* __restrict__ Wcm, const float* __restrict__ bcm,
    const float* __restrict__ Wom, const float* __restrict__ bom,
    float* __restrict__ out)
{
    const int b = blockIdx.x;
    const int t = threadIdx.x;
    const bool isDet = (b < NDBLK);
    const int p0 = b * GPB;                 // base det point (det blocks)
    const int m0 = (b - NDBLK) * GPB;       // base map index (map blocks)

    __shared__ int4   s_off4[101];          // slots g*25+tt (tt<24) + dummy 100
    __shared__ float4 s_w4[101];
    __shared__ int    s_flist[128];
    __shared__ int    s_cnt[4];
    __shared__ int    s_pref[5];
    __shared__ int    s_npad;
    __shared__ float4 s_vec4[CDIM];         // agg, [k] -> (g0,g1,g2,g3)
    __shared__ float4 s_hid4[CDIM];         // hidden, same layout

    const int lane = t & 63;
    const int g = t >> 6;                   // wave id = point-in-block

    // ---- setup: wave g, lanes 0..23 handle point g's (cam,lvl) tiles ----
    bool pred = false;
    int rank_reg = 0;
    {
        if (lane < 24) {
            // homogeneous point for point g (redundant per lane; L1-hot)
            float h0, h1, h2;
            if (isDet) {
                const int p = p0 + g;
                h0 = det3d[p * 3 + 0];
                h1 = det3d[p * 3 + 1];
                h2 = det3d[p * 3 + 2];
            } else {
                const int mi = m0 + g;
                float cx = 0.f, cy = 0.f;
                #pragma unroll
                for (int j = 0; j < NPTS; ++j) {
                    cx += mapanch[(mi * NPTS + j) * 2 + 0];
                    cy += mapanch[(mi * NPTS + j) * 2 + 1];
                }
                h0 = cx / (float)NPTS;
                h1 = cy / (float)NPTS;
                h2 = 0.f;
            }
            const int cam = lane >> 2, l = lane & 3;
            float pc[3];
            #pragma unroll
            for (int i = 0; i < 3; ++i) {
                pc[i] = Ein[cam * 16 + i * 4 + 0] * h0
                      + Ein[cam * 16 + i * 4 + 1] * h1
                      + Ein[cam * 16 + i * 4 + 2] * h2
                      + Ein[cam * 16 + i * 4 + 3] * 1.f;
            }
            const float q0 = Kin[cam*9+0]*pc[0] + Kin[cam*9+1]*pc[1] + Kin[cam*9+2]*pc[2];
            const float q1 = Kin[cam*9+3]*pc[0] + Kin[cam*9+4]*pc[1] + Kin[cam*9+5]*pc[2];
            const float q2 = Kin[cam*9+6]*pc[0] + Kin[cam*9+7]*pc[1] + Kin[cam*9+8]*pc[2];
            const float depth = q2;
            const float u = q0 / (depth + 1e-6f);
            const float v = q1 / (depth + 1e-6f);
            const bool valid = (depth > 0.1f);
            const float gx = u / 640.0f * 2.0f - 1.0f;
            const float gy = v / 480.0f * 2.0f - 1.0f;

            const int Hs[4] = {120, 60, 30, 15};
            const int Ws[4] = {160, 80, 40, 20};
            const int H = Hs[l], W = Ws[l];
            const float x = (gx + 1.f) * (W * 0.5f) - 0.5f;
            const float y = (gy + 1.f) * (H * 0.5f) - 0.5f;
            const float x0f = floorf(x), y0f = floorf(y);
            const float wx1 = x - x0f, wx0 = 1.f - wx1;
            const float wy1 = y - y0f, wy0 = 1.f - wy1;
            const float x1f = x0f + 1.f, y1f = y0f + 1.f;
            const bool bx0 = (x0f >= 0.f) && (x0f <= (float)(W - 1));
            const bool bx1 = (x1f >= 0.f) && (x1f <= (float)(W - 1));
            const bool by0 = (y0f >= 0.f) && (y0f <= (float)(H - 1));
            const bool by1 = (y1f >= 0.f) && (y1f <= (float)(H - 1));
            const int xc0 = (int)fminf(fmaxf(x0f, 0.f), (float)(W - 1));
            const int xc1 = (int)fminf(fmaxf(x1f, 0.f), (float)(W - 1));
            const int yc0 = (int)fminf(fmaxf(y0f, 0.f), (float)(H - 1));
            const int yc1 = (int)fminf(fmaxf(y1f, 0.f), (float)(H - 1));
            const int base = cam * CDIM * H * W;
            const int slot = g * 25 + lane;
            s_off4[slot] = make_int4(base + yc0 * W + xc0, base + yc0 * W + xc1,
                                     base + yc1 * W + xc0, base + yc1 * W + xc1);
            const float w0 = (bx0 && by0) ? wx0 * wy0 : 0.f;
            const float w1 = (bx1 && by0) ? wx1 * wy0 : 0.f;
            const float w2 = (bx0 && by1) ? wx0 * wy1 : 0.f;
            const float w3 = (bx1 && by1) ? wx1 * wy1 : 0.f;
            s_w4[slot] = make_float4(w0, w1, w2, w3);
            pred = valid && ((w0 + w1 + w2 + w3) != 0.f);
        }
        if (t == 24) {
            s_off4[100] = make_int4(0, 0, 0, 0);
            s_w4[100] = make_float4(0.f, 0.f, 0.f, 0.f);
        }
        const unsigned long long mask = __ballot(pred);
        rank_reg = __popcll(mask & ((1ull << lane) - 1ull));
        if (lane == 0) s_cnt[g] = __popcll(mask);
    }
    __syncthreads();
    if (t == 0) {
        int pr = 0;
        s_pref[0] = 0;
        #pragma unroll
        for (int gg = 0; gg < 4; ++gg) { pr += s_cnt[gg]; s_pref[gg + 1] = pr; }
        s_npad = (pr + 7) & ~7;
    }
    __syncthreads();
    if (pred) {
        const int l = lane & 3;
        s_flist[s_pref[g] + rank_reg] = (g * 25 + lane) | (l << 8) | (g << 10);
    }
    {
        const int ntot = s_pref[4];
        const int npad0 = s_npad;
        if (t < 8 && (ntot + t) < npad0) s_flist[ntot + t] = 100;  // dummy: slot100,l0,g0
    }
    __syncthreads();

    // ---- gather: branch-free chunks of 8 tiles, 32 loads in flight ----
    float acc0 = 0.f, acc1 = 0.f, acc2 = 0.f, acc3 = 0.f;
    const int npad = s_npad;
    for (int base = 0; base < npad; base += 8) {
        float v[8][4];
        int ej[8];
        #pragma unroll
        for (int j = 0; j < 8; ++j) {
            const int e = s_flist[base + j];
            ej[j] = e;
            const int slot = e & 255;
            const int l = (e >> 8) & 3;
            const float* f = lvlPtr(l, p2, p3, p4, p5);
            const int cHW = t * lvlHW(l);
            const int4 off = s_off4[slot];
            v[j][0] = f[off.x + cHW];
            v[j][1] = f[off.y + cHW];
            v[j][2] = f[off.z + cHW];
            v[j][3] = f[off.w + cHW];
        }
        #pragma unroll
        for (int j = 0; j < 8; ++j) {
            const int e = ej[j];
            const int slot = e & 255;
            const int gj = (e >> 10) & 3;
            const float4 w = s_w4[slot];
            const float c = w.x * v[j][0] + w.y * v[j][1] + w.z * v[j][2] + w.w * v[j][3];
            if      (gj == 0) acc0 += c;
            else if (gj == 1) acc1 += c;
            else if (gj == 2) acc2 += c;
            else              acc3 += c;
        }
    }
    s_vec4[t] = make_float4((acc0 * 0.25f) / 6.0f, (acc1 * 0.25f) / 6.0f,
                            (acc2 * 0.25f) / 6.0f, (acc3 * 0.25f) / 6.0f);
    __syncthreads();

    // ---- hidden GEMV for 4 points: W1 loaded once, reused x4 ----
    const float* __restrict__ W1 = isDet ? W1d : W1m;
    const float bb = (isDet ? b1d : b1m)[t];
    float h0a = bb, h1a = bb, h2a = bb, h3a = bb;
    for (int k0 = 0; k0 < CDIM; k0 += 32) {
        float wv[32];
        #pragma unroll
        for (int i = 0; i < 32; ++i) wv[i] = W1[(k0 + i) * CDIM + t];
        #pragma unroll
        for (int i = 0; i < 32; ++i) {
            const float4 x = s_vec4[k0 + i];
            h0a = fmaf(x.x, wv[i], h0a);
            h1a = fmaf(x.y, wv[i], h1a);
            h2a = fmaf(x.z, wv[i], h2a);
            h3a = fmaf(x.w, wv[i], h3a);
        }
    }
    s_hid4[t] = make_float4(fmaxf(h0a, 0.f), fmaxf(h1a, 0.f),
                            fmaxf(h2a, 0.f), fmaxf(h3a, 0.f));
    __syncthreads();

    // ---- heads: 16 lanes per output, weights loaded once, reused for 4 points ----
    const int grp = t >> 4;
    const int ln  = t & 15;
    const int nOut = isDet ? 15 : 43;
    const int nrep = isDet ? 1 : 3;
    for (int rep = 0; rep < nrep; ++rep) {
        const int o = grp + rep * 16;
        if (o < nOut) {
            const float* Wp; int stride, oo;
            if (isDet) {
                if (o < 4) { Wp = Wcd; stride = 4;  oo = o; }
                else       { Wp = Wod; stride = 11; oo = o - 4; }
            } else {
                if (o < 3) { Wp = Wcm; stride = 3;  oo = o; }
                else       { Wp = Wom; stride = 40; oo = o - 3; }
            }
            float wv[16];
            float4 xv[16];
            #pragma unroll
            for (int kk = 0; kk < 16; ++kk) wv[kk] = Wp[(ln + kk * 16) * stride + oo];
            #pragma unroll
            for (int kk = 0; kk < 16; ++kk) xv[kk] = s_hid4[ln + kk * 16];
            #pragma unroll
            for (int gp = 0; gp < 4; ++gp) {
                float sp = 0.f;
                #pragma unroll
                for (int kk = 0; kk < 16; ++kk) {
                    const float x = (gp == 0) ? xv[kk].x : (gp == 1) ? xv[kk].y
                                  : (gp == 2) ? xv[kk].z : xv[kk].w;
                    sp = fmaf(x, wv[kk], sp);
                }
                #pragma unroll
                for (int off = 1; off < 16; off <<= 1) sp += __shfl_xor(sp, off, 64);
                if (ln == 0) {
                    float bias; int ooff;
                    if (isDet) {
                        const int p = p0 + gp;
                        if (o < 4) { bias = bcd[oo];                              ooff = p * 4 + oo; }
                        else       { bias = bod[oo] + detfull[p * 11 + oo];       ooff = 3600 + p * 11 + oo; }
                    } else {
                        const int mi = m0 + gp;
                        if (o < 3) { bias = bcm[oo];                              ooff = 13500 + mi * 3 + oo; }
                        else       { bias = bom[oo] + mapanch[mi * 40 + oo];      ooff = 13800 + mi * 40 + oo; }
                    }
                    out[ooff] = sp + bias;
                }
            }
        }
    }
}

extern "C" void kernel_launch(void* const* d_in, const int* in_sizes, int n_in,
                              void* d_out, int out_size, void* d_ws, size_t ws_size,
                              hipStream_t stream) {
    const float* p2      = (const float*)d_in[0];
    const float* p3      = (const float*)d_in[1];
    const float* p4      = (const float*)d_in[2];
    const float* p5      = (const float*)d_in[3];
    const float* Kin     = (const float*)d_in[4];
    const float* Ein     = (const float*)d_in[5];
    const float* det3d   = (const float*)d_in[6];
    const float* detfull = (const float*)d_in[7];
    const float* mapanch = (const float*)d_in[8];
    const float* W1d     = (const float*)d_in[9];
    const float* b1d     = (const float*)d_in[10];
    const float* Wcd     = (const float*)d_in[11];
    const float* bcd     = (const float*)d_in[12];
    const float* Wod     = (const float*)d_in[13];
    const float* bod     = (const float*)d_in[14];
    const float* W1m     = (const float*)d_in[15];
    const float* b1m     = (const float*)d_in[16];
    const float* Wcm     = (const float*)d_in[17];
    const float* bcm     = (const float*)d_in[18];
    const float* Wom     = (const float*)d_in[19];
    const float* bom     = (const float*)d_in[20];
    float* out = (float*)d_out;

    autonav_fused<<<NBLK, 256, 0, stream>>>(
        p2, p3, p4, p5, Kin, Ein, det3d, detfull, mapanch,
        W1d, b1d, Wcd, bcd, Wod, bod, W1m, b1m, Wcm, bcm, Wom, bom, out);
}

// Round 9
// 55.951 us; speedup vs baseline: 1.1242x; 1.1242x over previous
//
#include <hip/hip_runtime.h>

#define CDIM 256
#define NDET 900
#define NMAP 100
#define NPTS 20
#define NBLK (NDET + NMAP)

__device__ __forceinline__ const float* lvlPtr(int l, const float* p2, const float* p3,
                                               const float* p4, const float* p5) {
    return (l == 0) ? p2 : (l == 1) ? p3 : (l == 2) ? p4 : p5;
}
__device__ __forceinline__ int lvlHW(int l) {
    return (l == 0) ? 19200 : (l == 1) ? 4800 : (l == 2) ? 1200 : 300;
}

__global__ __launch_bounds__(256, 4) void autonav_fused(
    const float* __restrict__ p2, const float* __restrict__ p3,
    const float* __restrict__ p4, const float* __restrict__ p5,
    const float* __restrict__ Kin, const float* __restrict__ Ein,
    const float* __restrict__ det3d, const float* __restrict__ detfull,
    const float* __restrict__ mapanch,
    const float* __restrict__ W1d, const float* __restrict__ b1d,
    const float* __restrict__ Wcd, const float* __restrict__ bcd,
    const float* __restrict__ Wod, const float* __restrict__ bod,
    const float* __restrict__ W1m, const float* __restrict__ b1m,
    const float* __restrict__ Wcm, const float* __restrict__ bcm,
    const float* __restrict__ Wom, const float* __restrict__ bom,
    float* __restrict__ out)
{
    const int pt = blockIdx.x;      // 0..999: 0..899 det, 900..999 map
    const int t  = threadIdx.x;     // channel
    const bool isDet = (pt < NDET);
    const int m = pt - NDET;

    __shared__ int   s_off[25][4];  // 24 real tiles + 1 zero-weight dummy
    __shared__ float s_w[25][4];
    __shared__ int   s_list[32];    // padded compact list
    __shared__ int   s_n;           // padded count (multiple of 8)
    __shared__ float s_vec[CDIM];   // agg
    __shared__ float s_hid[CDIM];   // hidden

    // ---- single setup phase: wave 0, threads 0..24 ----
    if (t < 25) {
        float h0, h1, h2;
        if (isDet) {
            h0 = det3d[pt * 3 + 0];
            h1 = det3d[pt * 3 + 1];
            h2 = det3d[pt * 3 + 2];
        } else {
            float cx = 0.f, cy = 0.f;
            #pragma unroll
            for (int j = 0; j < NPTS; ++j) {
                cx += mapanch[(m * NPTS + j) * 2 + 0];
                cy += mapanch[(m * NPTS + j) * 2 + 1];
            }
            h0 = cx / (float)NPTS;
            h1 = cy / (float)NPTS;
            h2 = 0.f;
        }

        bool pred = false;
        if (t < 24) {
            const int cam = t >> 2, l = t & 3;
            float pc[3];
            #pragma unroll
            for (int i = 0; i < 3; ++i) {
                pc[i] = Ein[cam * 16 + i * 4 + 0] * h0
                      + Ein[cam * 16 + i * 4 + 1] * h1
                      + Ein[cam * 16 + i * 4 + 2] * h2
                      + Ein[cam * 16 + i * 4 + 3] * 1.f;
            }
            const float q0 = Kin[cam*9+0]*pc[0] + Kin[cam*9+1]*pc[1] + Kin[cam*9+2]*pc[2];
            const float q1 = Kin[cam*9+3]*pc[0] + Kin[cam*9+4]*pc[1] + Kin[cam*9+5]*pc[2];
            const float q2 = Kin[cam*9+6]*pc[0] + Kin[cam*9+7]*pc[1] + Kin[cam*9+8]*pc[2];
            const float depth = q2;
            const float u = q0 / (depth + 1e-6f);
            const float v = q1 / (depth + 1e-6f);
            const bool valid = (depth > 0.1f);
            const float gx = u / 640.0f * 2.0f - 1.0f;
            const float gy = v / 480.0f * 2.0f - 1.0f;

            const int Hs[4] = {120, 60, 30, 15};
            const int Ws[4] = {160, 80, 40, 20};
            const int H = Hs[l], W = Ws[l];
            const float x = (gx + 1.f) * (W * 0.5f) - 0.5f;
            const float y = (gy + 1.f) * (H * 0.5f) - 0.5f;
            const float x0f = floorf(x), y0f = floorf(y);
            const float wx1 = x - x0f, wx0 = 1.f - wx1;
            const float wy1 = y - y0f, wy0 = 1.f - wy1;
            const float x1f = x0f + 1.f, y1f = y0f + 1.f;
            const bool bx0 = (x0f >= 0.f) && (x0f <= (float)(W - 1));
            const bool bx1 = (x1f >= 0.f) && (x1f <= (float)(W - 1));
            const bool by0 = (y0f >= 0.f) && (y0f <= (float)(H - 1));
            const bool by1 = (y1f >= 0.f) && (y1f <= (float)(H - 1));
            const int xc0 = (int)fminf(fmaxf(x0f, 0.f), (float)(W - 1));
            const int xc1 = (int)fminf(fmaxf(x1f, 0.f), (float)(W - 1));
            const int yc0 = (int)fminf(fmaxf(y0f, 0.f), (float)(H - 1));
            const int yc1 = (int)fminf(fmaxf(y1f, 0.f), (float)(H - 1));
            const int base = cam * CDIM * H * W;
            s_off[t][0] = base + yc0 * W + xc0;
            s_off[t][1] = base + yc0 * W + xc1;
            s_off[t][2] = base + yc1 * W + xc0;
            s_off[t][3] = base + yc1 * W + xc1;
            const float w0 = (bx0 && by0) ? wx0 * wy0 : 0.f;
            const float w1 = (bx1 && by0) ? wx1 * wy0 : 0.f;
            const float w2 = (bx0 && by1) ? wx0 * wy1 : 0.f;
            const float w3 = (bx1 && by1) ? wx1 * wy1 : 0.f;
            s_w[t][0] = w0; s_w[t][1] = w1; s_w[t][2] = w2; s_w[t][3] = w3;
            pred = valid && ((w0 + w1 + w2 + w3) != 0.f);
        } else {
            s_off[24][0] = 0; s_off[24][1] = 0; s_off[24][2] = 0; s_off[24][3] = 0;
            s_w[24][0] = 0.f; s_w[24][1] = 0.f; s_w[24][2] = 0.f; s_w[24][3] = 0.f;
        }

        const unsigned long long mask = __ballot(pred);
        const int n = __popcll(mask);
        const int rank = __popcll(mask & ((1ull << t) - 1ull));
        if (pred) s_list[rank] = t;
        const int npad = (n + 7) & ~7;
        if (t < 8 && (n + t) < npad) s_list[n + t] = 24;
        if (t == 0) s_n = npad;
    }
    __syncthreads();

    // ---- gather: branch-free chunks of 8 tiles (32 loads in flight) ----
    float acc = 0.f;
    const int npad = s_n;
    for (int base = 0; base < npad; base += 8) {
        float v[8][4];
        int tj[8];
        #pragma unroll
        for (int j = 0; j < 8; ++j) {
            const int tt = s_list[base + j];
            tj[j] = tt;
            const int l = tt & 3;
            const float* f = lvlPtr(l, p2, p3, p4, p5);
            const int cHW = t * lvlHW(l);
            v[j][0] = f[s_off[tt][0] + cHW];
            v[j][1] = f[s_off[tt][1] + cHW];
            v[j][2] = f[s_off[tt][2] + cHW];
            v[j][3] = f[s_off[tt][3] + cHW];
        }
        #pragma unroll
        for (int j = 0; j < 8; ++j) {
            const int tt = tj[j];
            acc += s_w[tt][0] * v[j][0] + s_w[tt][1] * v[j][1]
                 + s_w[tt][2] * v[j][2] + s_w[tt][3] * v[j][3];
        }
    }
    const float agg = (acc * 0.25f) / 6.0f;

    s_vec[t] = agg;
    __syncthreads();

    // ---- hidden GEMV: double-buffered 32-deep W1 batches (real MLP) ----
    const float* __restrict__ W1 = isDet ? W1d : W1m;
    const float* __restrict__ b1 = isDet ? b1d : b1m;
    float hsum = b1[t];
    const float4* sv4 = (const float4*)s_vec;
    float wvA[32], wvB[32];
    #pragma unroll
    for (int i = 0; i < 32; ++i) wvA[i] = W1[i * CDIM + t];
    #pragma unroll
    for (int k0 = 0; k0 < CDIM; k0 += 64) {
        #pragma unroll
        for (int i = 0; i < 32; ++i) wvB[i] = W1[(k0 + 32 + i) * CDIM + t];
        #pragma unroll
        for (int i = 0; i < 8; ++i) {
            const float4 x = sv4[(k0 >> 2) + i];
            hsum = fmaf(x.x, wvA[4 * i + 0], hsum);
            hsum = fmaf(x.y, wvA[4 * i + 1], hsum);
            hsum = fmaf(x.z, wvA[4 * i + 2], hsum);
            hsum = fmaf(x.w, wvA[4 * i + 3], hsum);
        }
        if (k0 + 64 < CDIM) {
            #pragma unroll
            for (int i = 0; i < 32; ++i) wvA[i] = W1[(k0 + 64 + i) * CDIM + t];
        }
        #pragma unroll
        for (int i = 0; i < 8; ++i) {
            const float4 x = sv4[(k0 >> 2) + 8 + i];
            hsum = fmaf(x.x, wvB[4 * i + 0], hsum);
            hsum = fmaf(x.y, wvB[4 * i + 1], hsum);
            hsum = fmaf(x.z, wvB[4 * i + 2], hsum);
            hsum = fmaf(x.w, wvB[4 * i + 3], hsum);
        }
    }
    s_hid[t] = fmaxf(hsum, 0.f);
    __syncthreads();

    // ---- output heads: 16 lanes per output, batched loads + shfl reduce ----
    const int g  = t >> 4;   // group 0..15
    const int ln = t & 15;   // lane in group
    const int nOut = isDet ? 15 : 43;
    const int nrep = isDet ? 1 : 3;
    for (int rep = 0; rep < nrep; ++rep) {
        const int o = g + rep * 16;
        if (o < nOut) {      // uniform across the 16-lane group
            const float* Wp; int stride, oo, ooff; float bias;
            if (isDet) {
                if (o < 4) { Wp = Wcd; stride = 4;  oo = o;     ooff = pt * 4 + oo;         bias = bcd[oo]; }
                else       { Wp = Wod; stride = 11; oo = o - 4; ooff = 3600 + pt * 11 + oo; bias = bod[oo] + detfull[pt * 11 + oo]; }
            } else {
                if (o < 3) { Wp = Wcm; stride = 3;  oo = o;     ooff = 13500 + m * 3 + oo;  bias = bcm[oo]; }
                else       { Wp = Wom; stride = 40; oo = o - 3; ooff = 13800 + m * 40 + oo; bias = bom[oo] + mapanch[m * 40 + oo]; }
            }
            float wv[16], xv[16];
            #pragma unroll
            for (int kk = 0; kk < 16; ++kk) wv[kk] = Wp[(ln + kk * 16) * stride + oo];
            #pragma unroll
            for (int kk = 0; kk < 16; ++kk) xv[kk] = s_hid[ln + kk * 16];
            float sp = 0.f;
            #pragma unroll
            for (int kk = 0; kk < 16; ++kk) sp = fmaf(xv[kk], wv[kk], sp);
            #pragma unroll
            for (int off = 1; off < 16; off <<= 1) sp += __shfl_xor(sp, off, 64);
            if (ln == 0) out[ooff] = sp + bias;
        }
    }
}

extern "C" void kernel_launch(void* const* d_in, const int* in_sizes, int n_in,
                              void* d_out, int out_size, void* d_ws, size_t ws_size,
                              hipStream_t stream) {
    const float* p2      = (const float*)d_in[0];
    const float* p3      = (const float*)d_in[1];
    const float* p4      = (const float*)d_in[2];
    const float* p5      = (const float*)d_in[3];
    const float* Kin     = (const float*)d_in[4];
    const float* Ein     = (const float*)d_in[5];
    const float* det3d   = (const float*)d_in[6];
    const float* detfull = (const float*)d_in[7];
    const float* mapanch = (const float*)d_in[8];
    const float* W1d     = (const float*)d_in[9];
    const float* b1d     = (const float*)d_in[10];
    const float* Wcd     = (const float*)d_in[11];
    const float* bcd     = (const float*)d_in[12];
    const float* Wod     = (const float*)d_in[13];
    const float* bod     = (const float*)d_in[14];
    const float* W1m     = (const float*)d_in[15];
    const float* b1m     = (const float*)d_in[16];
    const float* Wcm     = (const float*)d_in[17];
    const float* bcm     = (const float*)d_in[18];
    const float* Wom     = (const float*)d_in[19];
    const float* bom     = (const float*)d_in[20];
    float* out = (float*)d_out;

    autonav_fused<<<NBLK, 256, 0, stream>>>(
        p2, p3, p4, p5, Kin, Ein, det3d, detfull, mapanch,
        W1d, b1d, Wcd, bcd, Wod, bod, W1m, b1m, Wcm, bcm, Wom, bom, out);
}